// Round 6
// baseline (786.947 us; speedup 1.0000x reference)
//
#include <hip/hip_runtime.h>
#include <hip/hip_bf16.h>

typedef unsigned short u16;
typedef signed char i8;
typedef __attribute__((ext_vector_type(4))) float f32x4;
typedef __attribute__((ext_vector_type(4))) int i32x4;
typedef __attribute__((ext_vector_type(8))) short bf16x8;
typedef __attribute__((ext_vector_type(2))) unsigned int u32x2;

#define HID 256
#define NG 1024
#define TSTEPS 512
#define BATCH 256
#define CH 16          // steps per chunk
#define NCH 32         // chunks (CH*NCH = 512)
#define BB 8           // batch rows per rec block (2 cells/lane, 2x A-row duplication)
#define HSTR 272       // h_lds row stride bytes (17*16: 8 rows hit distinct bank phases)
#define LOG2E 1.4426950408889634f
#define PRE_TSTR 262144   // per-t' element stride in pre: 32 btiles * 4 j * 2048 (u*8+kb)
#define H0C_TSTR 65536    // per-t element stride in h0c frag layout [kk][bt][kgrp][col][e]

// fused-stage block roles (R5 post-mortem: rec BB=4 wasted CUs on 4x MFMA dup;
// BB=8 halves rec blocks, freeing 64 CUs for gemm1 which is the measured gate)
#define RECN 64        // rec blocks [0,64): layer = bid>>5, btile = bid&31
#define GB0  64        // gemm0 blocks [64,96)
#define GB1  96        // gemm1 blocks [96,224): (tp, j, bthalf)
#define NBLK 224

#define MFMA_BF16(a, b, c) __builtin_amdgcn_mfma_f32_16x16x32_bf16((a), (b), (c), 0, 0, 0)
#define MFMA_I8(a, b, c)   __builtin_amdgcn_mfma_i32_16x16x64_i8((a), (b), (c), 0, 0, 0)

__device__ __forceinline__ float rcpf_(float x) {
#if __has_builtin(__builtin_amdgcn_rcpf)
    return __builtin_amdgcn_rcpf(x);
#else
    return 1.f / x;
#endif
}
__device__ __forceinline__ float exp2_(float x) {
#if __has_builtin(__builtin_amdgcn_exp2f)
    return __builtin_amdgcn_exp2f(x);
#else
    return exp2f(x);
#endif
}
__device__ __forceinline__ float sigm2(float y) { return rcpf_(1.f + exp2_(-y)); }
__device__ __forceinline__ float tanh2(float y2) { return fmaf(-2.f, rcpf_(exp2_(y2) + 1.f), 1.f); }
__device__ __forceinline__ u16 f2bf(float v){ __hip_bfloat16 h=__float2bfloat16(v); return __builtin_bit_cast(u16,h); }
__device__ __forceinline__ float bf2f(u16 u){ unsigned x=((unsigned)u)<<16; return __builtin_bit_cast(float,x); }

// ---------------------------------------------------------------------------
// prep_a: per-gate-row i8 scales for Whh0/Whh1; log2e folded into dequant
// scales and biases. (unchanged)
// ---------------------------------------------------------------------------
__global__ void prep_a(const float* __restrict__ Whh0, const float* __restrict__ Whh1,
                       const float* __restrict__ bih0, const float* __restrict__ bhh0,
                       const float* __restrict__ bih1, const float* __restrict__ bhh1,
                       float* __restrict__ qs0, float* __restrict__ dq0s,
                       float* __restrict__ qs1, float* __restrict__ dq1s,
                       float* __restrict__ b0s, float* __restrict__ b1s) {
    int r = blockIdx.x * blockDim.x + threadIdx.x;
    if (r >= NG) return;
    float m0 = 1e-20f, m1 = 1e-20f;
    for (int k = 0; k < HID; k++) {
        m0 = fmaxf(m0, fabsf(Whh0[r * HID + k]));
        m1 = fmaxf(m1, fabsf(Whh1[r * HID + k]));
    }
    qs0[r] = 127.f / m0;   dq0s[r] = m0 / 16129.f * LOG2E;
    qs1[r] = 127.f / m1;   dq1s[r] = m1 / 16129.f * LOG2E;
    b0s[r] = (bih0[r] + bhh0[r]) * LOG2E;
    b1s[r] = (bih1[r] + bhh1[r]) * LOG2E;
}

// ---------------------------------------------------------------------------
// prep_b: i8 frag packs for Whh0/Whh1; bf16 Wih1 frags (x LOG2E); bf16 Wih0
// frags (x LOG2E, K pad 5->32); x padded to 8 bf16/token; zeroed states.
// (unchanged)
// ---------------------------------------------------------------------------
__global__ void prep_b(const float* __restrict__ x,
    const float* __restrict__ Wih0, const float* __restrict__ Whh0,
    const float* __restrict__ Wih1, const float* __restrict__ Whh1,
    const float* __restrict__ qs0, const float* __restrict__ qs1,
    i8* __restrict__ wi80, i8* __restrict__ wi81,
    u16* __restrict__ wih1f, u16* __restrict__ wih0f,
    i8* __restrict__ hs0, i8* __restrict__ hs1,
    float* __restrict__ cs0, float* __restrict__ cs1, u16* __restrict__ xpad)
{
    const int stride = gridDim.x * blockDim.x;
    const int tid = blockIdx.x * blockDim.x + threadIdx.x;
    for (int i = tid; i < NG * HID; i += stride) {   // i8 packs (recurrent)
        int e = i & 15, l = (i >> 4) & 63, kc = (i >> 10) & 3, gt = i >> 12;
        int row = 16 * gt + (l & 15);
        int k = kc * 64 + (l >> 4) * 16 + e;
        float q0 = __builtin_rintf(Whh0[row * HID + k] * qs0[row]);
        float q1 = __builtin_rintf(Whh1[row * HID + k] * qs1[row]);
        wi80[i] = (i8)fminf(fmaxf(q0, -127.f), 127.f);
        wi81[i] = (i8)fminf(fmaxf(q1, -127.f), 127.f);
    }
    for (int i = tid; i < NG * HID; i += stride) {   // Wih1 bf16 frags, scaled
        int gt = i >> 12, kk = (i >> 9) & 7, l = (i >> 3) & 63, e = i & 7;
        wih1f[i] = f2bf(Wih1[(16 * gt + (l & 15)) * HID + kk * 32 + (l >> 4) * 8 + e] * LOG2E);
    }
    for (int i = tid; i < 32768; i += stride) {      // Wih0 bf16 frags, scaled
        int gt = i >> 9, l = (i >> 3) & 63, e = i & 7;
        int k = (l >> 4) * 8 + e;
        wih0f[i] = (k < 5) ? f2bf(Wih0[(16 * gt + (l & 15)) * 5 + k] * LOG2E) : (u16)0;
    }
    for (int i = tid; i < TSTEPS * BATCH * 8; i += stride) {  // x padded to 8, token-major
        int tok = i >> 3, k = i & 7, t = tok >> 8, b = tok & 255;
        xpad[i] = (k < 5) ? f2bf(x[((size_t)b * TSTEPS + t) * 5 + k]) : (u16)0;
    }
    for (int i = tid; i < BATCH * HID; i += stride) { hs0[i] = 0; hs1[i] = 0; cs0[i] = 0.f; cs1[i] = 0.f; }
}

// ---------------------------------------------------------------------------
// stage_fused(L): four pipeline roles on disjoint blocks (gemms overlap recs):
//   blocks [0,32):    rec layer0, chunk L-1   (reads pre0, writes h0c)
//   blocks [32,64):   rec layer1, chunk L-3   (reads pre1)
//   blocks [64,96):   gemm0: pre0(chunk L)   = log2e*(Wih0 x + b0)
//   blocks [96,224):  gemm1: pre1(chunk L-2) = log2e*(Wih1 h0 + b1)
//
// pre layout (BB=8): idx = ((t*32 + btile)*4 + j)*2048 + u*8 + kb,
//   gate = j*256+u, batch = btile*8+kb. Rec lane (u, kgrp) owns batches
//   2kgrp, 2kgrp+1 (A row r = batch r>>1; acc rows 4kgrp..4kgrp+3 are the
//   dup pairs -> use acc[j][0] and acc[j][2]); its per-j pre pair is ONE
//   aligned u32. gemm C-frag batch = btg*16+kgrp*4+rr -> kb = (kgrp&1)*4+rr
//   (4 consecutive) -> one 8B store, 2x256B segments/instr. Bit-identical.
// ---------------------------------------------------------------------------
__global__ __launch_bounds__(1024) __attribute__((amdgpu_waves_per_eu(4, 4)))
void stage_fused(int L,
    const u16* __restrict__ xpad8, const u16* __restrict__ wih0f, const float* __restrict__ b0s,
    const u16* __restrict__ wih1f, const float* __restrict__ b1s,
    u16* __restrict__ p0w, const u16* __restrict__ p0r,
    u16* __restrict__ h0w, const u16* __restrict__ h0r,
    u16* __restrict__ p1w, const u16* __restrict__ p1r,
    const i8* __restrict__ wi80, const i8* __restrict__ wi81,
    const float* __restrict__ dq0s, const float* __restrict__ dq1s,
    i8* __restrict__ hs0, i8* __restrict__ hs1,
    float* __restrict__ cs0, float* __restrict__ cs1)
{
    __shared__ i8 h_lds[2][BB * HSTR];
    const int bid = blockIdx.x;
    const int tid = threadIdx.x, lane = tid & 63;
    const int col = lane & 15, kgrp = lane >> 4;

    if (bid < RECN) {
        // ---------------- recurrent role (BB=8, 2 cells/lane) ----------------
        const int layer = bid >> 5;
        if (layer == 0) { if (L < 1 || L > NCH) return; }
        else            { if (L < 3 || L > NCH + 2) return; }
        const int btile = bid & 31;
        const u16* pre   = layer ? p1r : p0r;
        const i8*  wi8   = layer ? wi81 : wi80;
        const float* dq  = layer ? dq1s : dq0s;
        i8*    h_state   = layer ? hs1 : hs0;
        float* c_state   = layer ? cs1 : cs0;
        const int w = tid >> 6;
        const int b0 = btile * BB;
        const int u = w * 16 + col;          // h-unit this lane owns
        const int kb0 = 2 * kgrp;            // lane's two batches: kb0, kb0+1

        float sc[4];
        i32x4 wv[4][4];                      // 64 VGPRs resident weights
#pragma unroll
        for (int j = 0; j < 4; j++) {
            const int gt = 16 * j + w;
            sc[j] = dq[gt * 16 + col];
#pragma unroll
            for (int kc = 0; kc < 4; kc++)
                wv[j][kc] = ((const i32x4*)wi8)[(gt * 4 + kc) * 64 + lane];
        }
        if (tid < 64 * BB) {
            const int rrow = tid >> 6, cc = (tid & 63) * 4;
            *(int*)&h_lds[0][rrow * HSTR + cc] = *(const int*)&h_state[(b0 + rrow) * HID + cc];
        }
        float c0 = c_state[(size_t)(b0 + kb0) * HID + u];
        float c1 = c_state[(size_t)(b0 + kb0 + 1) * HID + u];

        // pre base for this lane (element units); per-j pair load is one u32
        const u16* pb = pre + ((size_t)btile << 13) + u * 8 + kb0;
        unsigned pvA[4], pvB[4];
#pragma unroll
        for (int j = 0; j < 4; j++) pvA[j] = *(const unsigned*)(pb + (j << 11));
        // h0c store bases (frag layout [t][kk=u>>5][bt][kgrpg=(u>>3)&3][colg][e=u&7])
        const size_t h0b0 = ((((size_t)(w >> 1) * 16 + (btile >> 1)) * 4
                             + ((w & 1) * 2 + (col >> 3))) * 16
                            + ((btile & 1) * 8 + kb0)) * 8 + (col & 7);
        const size_t h0b1 = h0b0 + 8;        // kb0+1 -> +1 colg slot = +8 elements
        __syncthreads();

#define REC_STEP(T, CUR, PVC, PVN) do {                                             \
        _Pragma("unroll")                                                           \
        for (int j = 0; j < 4; j++)                                                 \
            asm volatile("" : "+v"(wv[j][0]), "+v"(wv[j][1]),                       \
                              "+v"(wv[j][2]), "+v"(wv[j][3]));                      \
        i32x4 acc[4];                                                               \
        _Pragma("unroll")                                                           \
        for (int j = 0; j < 4; j++) acc[j] = (i32x4){0, 0, 0, 0};                   \
        _Pragma("unroll")                                                           \
        for (int kc = 0; kc < 4; kc++) {                                            \
            i32x4 a_ = *(const i32x4*)&h_lds[CUR][(col >> 1) * HSTR + kc * 64 + kgrp * 16]; \
            _Pragma("unroll")                                                       \
            for (int j = 0; j < 4; j++) acc[j] = MFMA_I8(a_, wv[j][kc], acc[j]);    \
        }                                                                           \
        const int tn_ = ((T) + 1 < CH) ? (T) + 1 : (T);                             \
        _Pragma("unroll")                                                           \
        for (int j = 0; j < 4; j++)                                                 \
            PVN[j] = *(const unsigned*)(pb + (size_t)tn_ * PRE_TSTR + (j << 11));   \
        const float yi0 = fmaf((float)acc[0][0], sc[0], bf2f((u16)(PVC[0] & 0xffff))); \
        const float yf0 = fmaf((float)acc[1][0], sc[1], bf2f((u16)(PVC[1] & 0xffff))); \
        const float yg0 = fmaf((float)acc[2][0], sc[2], bf2f((u16)(PVC[2] & 0xffff))); \
        const float yo0 = fmaf((float)acc[3][0], sc[3], bf2f((u16)(PVC[3] & 0xffff))); \
        const float yi1 = fmaf((float)acc[0][2], sc[0], bf2f((u16)(PVC[0] >> 16)));    \
        const float yf1 = fmaf((float)acc[1][2], sc[1], bf2f((u16)(PVC[1] >> 16)));    \
        const float yg1 = fmaf((float)acc[2][2], sc[2], bf2f((u16)(PVC[2] >> 16)));    \
        const float yo1 = fmaf((float)acc[3][2], sc[3], bf2f((u16)(PVC[3] >> 16)));    \
        const float iv0 = sigm2(yi0), fv0 = sigm2(yf0), ov0 = sigm2(yo0);           \
        const float gv0 = tanh2(yg0 + yg0);                                         \
        c0 = fmaf(fv0, c0, iv0 * gv0);                                              \
        const float hv0 = ov0 * tanh2(c0 * (2.f * LOG2E));                          \
        const float iv1 = sigm2(yi1), fv1 = sigm2(yf1), ov1 = sigm2(yo1);           \
        const float gv1 = tanh2(yg1 + yg1);                                         \
        c1 = fmaf(fv1, c1, iv1 * gv1);                                              \
        const float hv1 = ov1 * tanh2(c1 * (2.f * LOG2E));                          \
        h_lds[(CUR) ^ 1][kb0 * HSTR + u] = (i8)__float2int_rn(hv0 * 127.f);         \
        h_lds[(CUR) ^ 1][(kb0 + 1) * HSTR + u] = (i8)__float2int_rn(hv1 * 127.f);   \
        if (layer == 0) {                                                           \
            h0w[h0b0 + (size_t)(T) * H0C_TSTR] = f2bf(hv0);                         \
            h0w[h0b1 + (size_t)(T) * H0C_TSTR] = f2bf(hv1);                         \
        }                                                                           \
        asm volatile("s_waitcnt lgkmcnt(0)" ::: "memory");                          \
        __builtin_amdgcn_s_barrier();                                               \
        __builtin_amdgcn_sched_barrier(0);                                          \
    } while (0)

#pragma unroll 1
        for (int t2 = 0; t2 < CH; t2 += 2) {
            REC_STEP(t2,     0, pvA, pvB);
            REC_STEP(t2 + 1, 1, pvB, pvA);
        }
#undef REC_STEP

        c_state[(size_t)(b0 + kb0) * HID + u] = c0;
        c_state[(size_t)(b0 + kb0 + 1) * HID + u] = c1;
        if (tid < 64 * BB) {
            const int rrow = tid >> 6, cc = (tid & 63) * 4;
            *(int*)&h_state[(b0 + rrow) * HID + cc] = *(const int*)&h_lds[0][rrow * HSTR + cc];
        }
        return;
    } else if (bid < GB1) {
        // ---------------- gemm0: pre0(chunk L), operand-swapped ----------------
        if (L >= NCH) return;
        const int g = bid - GB0;             // 0..31
        const int tp = g >> 1, bh = g & 1;   // t' 0..15, batch half
        const int w = tid >> 6;              // wave 0..15
        const int j = w >> 2;                // pre j-chunk, constant per wave
        float bias[4];
        bf16x8 wv4[4];
#pragma unroll
        for (int tm = 0; tm < 4; tm++) {
            const int tile = w * 4 + tm;     // 16-gate tile 0..63
            bias[tm] = b0s[tile * 16 + col];
            wv4[tm] = *(const bf16x8*)&wih0f[((size_t)tile * 64 + lane) * 8];
        }
        const u16* Ab = xpad8 + ((size_t)L * CH + tp) * BATCH * 8;
#pragma unroll 1
        for (int bt = 0; bt < 8; bt++) {
            const int btg = bh * 8 + bt;     // global 16-batch tile
            bf16x8 af = {0, 0, 0, 0, 0, 0, 0, 0};   // K beyond 8 is zero-padded
            if (kgrp == 0) af = *(const bf16x8*)&Ab[(btg * 16 + col) * 8];
            f32x4 acc[4];
#pragma unroll
            for (int tm = 0; tm < 4; tm++) acc[tm] = (f32x4){bias[tm], bias[tm], bias[tm], bias[tm]};
#pragma unroll
            for (int tm = 0; tm < 4; tm++) acc[tm] = MFMA_BF16(af, wv4[tm], acc[tm]);
            // batch = btg*16+kgrp*4+rr -> btile = btg*2+(kgrp>>1), kb = (kgrp&1)*4+rr
#pragma unroll
            for (int tm = 0; tm < 4; tm++) {
                const int ul = ((w & 3) * 4 + tm) * 16 + col;   // u within j-chunk
                const size_t off = (((size_t)tp * 32 + btg * 2 + (kgrp >> 1)) * 4 + j) * 2048
                                   + ul * 8 + (kgrp & 1) * 4;
                u32x2 pk;
                pk.x = (unsigned)f2bf(acc[tm][0]) | ((unsigned)f2bf(acc[tm][1]) << 16);
                pk.y = (unsigned)f2bf(acc[tm][2]) | ((unsigned)f2bf(acc[tm][3]) << 16);
                *(u32x2*)&p0w[off] = pk;
            }
        }
        return;
    } else {
        // ---------------- gemm1: pre1(chunk L-2), 128 blocks, 16 waves, 8 bt ----------------
        if (L < 2 || L > NCH + 1) return;
        const int g = bid - GB1;             // 0..127
        const int tp = g >> 3, j = (g >> 1) & 3, bh = g & 1;
        const int w = tid >> 6;              // wave = 16-gate tile within j
        const int gt = j * 16 + w;           // global 16-gate tile
        const float bias = b1s[gt * 16 + col];
        bf16x8 wv8[8];                       // 32 VGPRs resident weights
#pragma unroll
        for (int kk = 0; kk < 8; kk++)
            wv8[kk] = *(const bf16x8*)&wih1f[((size_t)(gt * 8 + kk) * 64 + lane) * 8];
        // A base: per (kk,bt) the wave reads 1024B coalesced from frag-layout h0c
        const u16* A0 = h0r + (size_t)tp * H0C_TSTR + (size_t)lane * 8;
#pragma unroll 1
        for (int bt8 = 0; bt8 < 8; bt8++) {
            const int bt = bh * 8 + bt8;
            bf16x8 a8[8];
#pragma unroll
            for (int kk = 0; kk < 8; kk++)
                a8[kk] = *(const bf16x8*)&A0[((size_t)kk * 16 + bt) * 512];
            f32x4 acc = (f32x4){bias, bias, bias, bias};
#pragma unroll
            for (int kk = 0; kk < 8; kk++)
                acc = MFMA_BF16(a8[kk], wv8[kk], acc);
            const int ul = w * 16 + col;     // u within j-chunk
            const size_t off = (((size_t)tp * 32 + bt * 2 + (kgrp >> 1)) * 4 + j) * 2048
                               + ul * 8 + (kgrp & 1) * 4;
            u32x2 pk;
            pk.x = (unsigned)f2bf(acc[0]) | ((unsigned)f2bf(acc[1]) << 16);
            pk.y = (unsigned)f2bf(acc[2]) | ((unsigned)f2bf(acc[3]) << 16);
            *(u32x2*)&p1w[off] = pk;
        }
        return;
    }
}

// ---------------------------------------------------------------------------
// head: y = sigmoid(relu(h_last) @ Wh^T + bh)
// ---------------------------------------------------------------------------
__global__ void head_kernel(const i8* __restrict__ hs1,
                            const float* __restrict__ Wh, const float* __restrict__ bh,
                            float* __restrict__ y) {
    int b = blockIdx.x;
    int l = threadIdx.x;
    const float inv127 = 1.f / 127.f;
    float hr[4];
#pragma unroll
    for (int i = 0; i < 4; ++i) hr[i] = fmaxf((float)hs1[b * HID + l + 64 * i] * inv127, 0.f);
    for (int o = 0; o < 3; ++o) {
        float s = 0.f;
#pragma unroll
        for (int i = 0; i < 4; ++i) s += hr[i] * Wh[o * HID + l + 64 * i];
        for (int off = 32; off > 0; off >>= 1) s += __shfl_down(s, off, 64);
        if (l == 0) y[b * 3 + o] = 1.f / (1.f + exp2_(-(s + bh[o]) * LOG2E));
    }
}

extern "C" void kernel_launch(void* const* d_in, const int* in_sizes, int n_in,
                              void* d_out, int out_size, void* d_ws, size_t ws_size,
                              hipStream_t stream) {
    const float* x    = (const float*)d_in[0];
    const float* Wih0 = (const float*)d_in[1];
    const float* Whh0 = (const float*)d_in[2];
    const float* bih0 = (const float*)d_in[3];
    const float* bhh0 = (const float*)d_in[4];
    const float* Wih1 = (const float*)d_in[5];
    const float* Whh1 = (const float*)d_in[6];
    const float* bih1 = (const float*)d_in[7];
    const float* bhh1 = (const float*)d_in[8];
    const float* Wh   = (const float*)d_in[9];
    const float* bh   = (const float*)d_in[10];

    char* ws = (char*)d_ws;
    i8*    wi80  = (i8*)(ws);                            // 256 KB
    i8*    wi81  = (i8*)(ws + ((size_t)256 << 10));      // 256 KB
    u16*   wih1f = (u16*)(ws + ((size_t)512 << 10));     // 512 KB
    u16*   wih0f = (u16*)(ws + ((size_t)1024 << 10));    // 64 KB
    float* qs0   = (float*)(ws + ((size_t)1088 << 10));
    float* dq0s  = (float*)(ws + ((size_t)1092 << 10));
    float* qs1   = (float*)(ws + ((size_t)1096 << 10));
    float* dq1s  = (float*)(ws + ((size_t)1100 << 10));
    float* b0s   = (float*)(ws + ((size_t)1104 << 10));
    float* b1s   = (float*)(ws + ((size_t)1108 << 10));
    i8*    hs0   = (i8*)(ws + ((size_t)1112 << 10));     // 64 KB
    i8*    hs1   = (i8*)(ws + ((size_t)1176 << 10));     // 64 KB
    float* cs0   = (float*)(ws + ((size_t)1240 << 10));  // 256 KB
    float* cs1   = (float*)(ws + ((size_t)1496 << 10));  // 256 KB
    u16*   xpad  = (u16*)(ws + ((size_t)1752 << 10));    // 2 MB  [tok][8] bf16
    u16*   h0c   = (u16*)(ws + ((size_t)3800 << 10));    // 2 x 2 MB (chunk parity)
    u16*   pre0  = (u16*)(ws + ((size_t)7896 << 10));    // 2 x 8 MB (chunk parity)
    u16*   pre1  = (u16*)(ws + ((size_t)24280 << 10));   // 2 x 8 MB -> total ~39.7 MB
    const size_t PRE_ELE = (size_t)CH * BATCH * NG;      // 4 Mi elements (8 MB)
    const size_t H0C_ELE = (size_t)CH * BATCH * HID;     // 1 Mi elements (2 MB)

    prep_a<<<4, 256, 0, stream>>>(Whh0, Whh1, bih0, bhh0, bih1, bhh1,
                                  qs0, dq0s, qs1, dq1s, b0s, b1s);
    prep_b<<<1024, 256, 0, stream>>>(x, Wih0, Whh0, Wih1, Whh1, qs0, qs1,
                                     wi80, wi81, wih1f, wih0f, hs0, hs1, cs0, cs1, xpad);
    // pipeline: gemm0(c=L) | rec0(c=L-1) | gemm1(c=L-2) | rec1(c=L-3)
    for (int L = 0; L <= NCH + 2; L++) {
        const size_t pA = (size_t)(L & 1), pB = pA ^ 1;
        stage_fused<<<NBLK, 1024, 0, stream>>>(L, xpad, wih0f, b0s, wih1f, b1s,
            pre0 + pA * PRE_ELE,        // gemm0 writes chunk L      (parity L)
            pre0 + pB * PRE_ELE,        // rec0 reads chunk L-1      (parity L-1)
            h0c  + pB * H0C_ELE,        // rec0 writes chunk L-1
            h0c  + pA * H0C_ELE,        // gemm1 reads chunk L-2     (parity L)
            pre1 + pA * PRE_ELE,        // gemm1 writes chunk L-2
            pre1 + pB * PRE_ELE,        // rec1 reads chunk L-3      (parity L-1)
            wi80, wi81, dq0s, dq1s, hs0, hs1, cs0, cs1);
    }
    head_kernel<<<BATCH, 64, 0, stream>>>(hs1, Wh, bh, (float*)d_out);
}

// Round 7
// 633.767 us; speedup vs baseline: 1.2417x; 1.2417x over previous
//
#include <hip/hip_runtime.h>
#include <hip/hip_bf16.h>

typedef unsigned short u16;
typedef signed char i8;
typedef __attribute__((ext_vector_type(4))) float f32x4;
typedef __attribute__((ext_vector_type(4))) int i32x4;
typedef __attribute__((ext_vector_type(8))) short bf16x8;
typedef __attribute__((ext_vector_type(2))) unsigned int u32x2;

#define HID 256
#define NG 1024
#define TSTEPS 512
#define BATCH 256
#define CH 16          // steps per chunk
#define NCH 32         // chunks (CH*NCH = 512)
#define BB 4           // batch rows per rec block (1 cell/lane via A-row duplication)
#define HSTR 288       // h_lds row stride bytes
#define LOG2E 1.4426950408889634f
#define PRE_TSTR 262144   // per-t' element stride in pre: 64 btiles * 4 j * 1024 (u*4+kb)
#define H0C_TSTR 65536    // per-t element stride in h0c frag layout [kk][bt][kgrp][col][e]

// fused-stage block roles (identical budget to the 745us R4 config)
#define GB0 128        // gemm0 blocks [128,160)
#define GB1 160        // gemm1 blocks [160,224)
#define NBLK 224

#define MFMA_BF16(a, b, c) __builtin_amdgcn_mfma_f32_16x16x32_bf16((a), (b), (c), 0, 0, 0)
#define MFMA_I8(a, b, c)   __builtin_amdgcn_mfma_i32_16x16x64_i8((a), (b), (c), 0, 0, 0)

__device__ __forceinline__ float rcpf_(float x) {
#if __has_builtin(__builtin_amdgcn_rcpf)
    return __builtin_amdgcn_rcpf(x);
#else
    return 1.f / x;
#endif
}
__device__ __forceinline__ float exp2_(float x) {
#if __has_builtin(__builtin_amdgcn_exp2f)
    return __builtin_amdgcn_exp2f(x);
#else
    return exp2f(x);
#endif
}
__device__ __forceinline__ float sigm2(float y) { return rcpf_(1.f + exp2_(-y)); }
__device__ __forceinline__ float tanh2(float y2) { return fmaf(-2.f, rcpf_(exp2_(y2) + 1.f), 1.f); }
__device__ __forceinline__ u16 f2bf(float v){ __hip_bfloat16 h=__float2bfloat16(v); return __builtin_bit_cast(u16,h); }
__device__ __forceinline__ float bf2f(u16 u){ unsigned x=((unsigned)u)<<16; return __builtin_bit_cast(float,x); }

// ---------------------------------------------------------------------------
// prep_a: per-gate-row i8 scales for Whh0/Whh1; log2e folded into dequant
// scales and biases. (unchanged)
// ---------------------------------------------------------------------------
__global__ void prep_a(const float* __restrict__ Whh0, const float* __restrict__ Whh1,
                       const float* __restrict__ bih0, const float* __restrict__ bhh0,
                       const float* __restrict__ bih1, const float* __restrict__ bhh1,
                       float* __restrict__ qs0, float* __restrict__ dq0s,
                       float* __restrict__ qs1, float* __restrict__ dq1s,
                       float* __restrict__ b0s, float* __restrict__ b1s) {
    int r = blockIdx.x * blockDim.x + threadIdx.x;
    if (r >= NG) return;
    float m0 = 1e-20f, m1 = 1e-20f;
    for (int k = 0; k < HID; k++) {
        m0 = fmaxf(m0, fabsf(Whh0[r * HID + k]));
        m1 = fmaxf(m1, fabsf(Whh1[r * HID + k]));
    }
    qs0[r] = 127.f / m0;   dq0s[r] = m0 / 16129.f * LOG2E;
    qs1[r] = 127.f / m1;   dq1s[r] = m1 / 16129.f * LOG2E;
    b0s[r] = (bih0[r] + bhh0[r]) * LOG2E;
    b1s[r] = (bih1[r] + bhh1[r]) * LOG2E;
}

// ---------------------------------------------------------------------------
// prep_b: i8 frag packs for Whh0/Whh1; bf16 Wih1 frags (x LOG2E); bf16 Wih0
// frags (x LOG2E, K pad 5->32); x padded to 8 bf16/token; zeroed states.
// (unchanged)
// ---------------------------------------------------------------------------
__global__ void prep_b(const float* __restrict__ x,
    const float* __restrict__ Wih0, const float* __restrict__ Whh0,
    const float* __restrict__ Wih1, const float* __restrict__ Whh1,
    const float* __restrict__ qs0, const float* __restrict__ qs1,
    i8* __restrict__ wi80, i8* __restrict__ wi81,
    u16* __restrict__ wih1f, u16* __restrict__ wih0f,
    i8* __restrict__ hs0, i8* __restrict__ hs1,
    float* __restrict__ cs0, float* __restrict__ cs1, u16* __restrict__ xpad)
{
    const int stride = gridDim.x * blockDim.x;
    const int tid = blockIdx.x * blockDim.x + threadIdx.x;
    for (int i = tid; i < NG * HID; i += stride) {   // i8 packs (recurrent)
        int e = i & 15, l = (i >> 4) & 63, kc = (i >> 10) & 3, gt = i >> 12;
        int row = 16 * gt + (l & 15);
        int k = kc * 64 + (l >> 4) * 16 + e;
        float q0 = __builtin_rintf(Whh0[row * HID + k] * qs0[row]);
        float q1 = __builtin_rintf(Whh1[row * HID + k] * qs1[row]);
        wi80[i] = (i8)fminf(fmaxf(q0, -127.f), 127.f);
        wi81[i] = (i8)fminf(fmaxf(q1, -127.f), 127.f);
    }
    for (int i = tid; i < NG * HID; i += stride) {   // Wih1 bf16 frags, scaled
        int gt = i >> 12, kk = (i >> 9) & 7, l = (i >> 3) & 63, e = i & 7;
        wih1f[i] = f2bf(Wih1[(16 * gt + (l & 15)) * HID + kk * 32 + (l >> 4) * 8 + e] * LOG2E);
    }
    for (int i = tid; i < 32768; i += stride) {      // Wih0 bf16 frags, scaled
        int gt = i >> 9, l = (i >> 3) & 63, e = i & 7;
        int k = (l >> 4) * 8 + e;
        wih0f[i] = (k < 5) ? f2bf(Wih0[(16 * gt + (l & 15)) * 5 + k] * LOG2E) : (u16)0;
    }
    for (int i = tid; i < TSTEPS * BATCH * 8; i += stride) {  // x padded to 8, token-major
        int tok = i >> 3, k = i & 7, t = tok >> 8, b = tok & 255;
        xpad[i] = (k < 5) ? f2bf(x[((size_t)b * TSTEPS + t) * 5 + k]) : (u16)0;
    }
    for (int i = tid; i < BATCH * HID; i += stride) { hs0[i] = 0; hs1[i] = 0; cs0[i] = 0.f; cs1[i] = 0.f; }
}

// ---------------------------------------------------------------------------
// stage_fused(L): four pipeline roles on disjoint blocks (gemms overlap recs):
//   blocks [0,64):    rec layer0, chunk L-1   (reads pre0, writes h0c)
//   blocks [64,128):  rec layer1, chunk L-3   (reads pre1)
//   blocks [128,160): gemm0: pre0(chunk L)   = log2e*(Wih0 x + b0)
//   blocks [160,224): gemm1: pre1(chunk L-2) = log2e*(Wih1 h0 + b1)
//
// R6 POST-MORTEM: R5/R6 both 787us with DIFFERENT gates (gemm1-latency vs
// rec-BB8-VALU) -- coincidence, not a wall. This round: rec back to BB=4
// (best measured, VALU 480 < MFMA-issue 1306 cyc/SIMD/step) + gemm1 keeps
// 16 waves (4/SIMD) but stages the shared A-tile through LDS double-buffered:
// per-block A traffic 2MB(L1-bound, ~15us = R4's gate) -> 128KB global +
// LDS reads at 2x L1 BW (~6us). Same A values, same kk order: bit-identical.
// ---------------------------------------------------------------------------
__global__ __launch_bounds__(1024) __attribute__((amdgpu_waves_per_eu(4, 4)))
void stage_fused(int L,
    const u16* __restrict__ xpad8, const u16* __restrict__ wih0f, const float* __restrict__ b0s,
    const u16* __restrict__ wih1f, const float* __restrict__ b1s,
    u16* __restrict__ p0w, const u16* __restrict__ p0r,
    u16* __restrict__ h0w, const u16* __restrict__ h0r,
    u16* __restrict__ p1w, const u16* __restrict__ p1r,
    const i8* __restrict__ wi80, const i8* __restrict__ wi81,
    const float* __restrict__ dq0s, const float* __restrict__ dq1s,
    i8* __restrict__ hs0, i8* __restrict__ hs1,
    float* __restrict__ cs0, float* __restrict__ cs1)
{
    __shared__ __align__(16) char smem[16384];   // gemm1: 2x8KB A dbuf; rec: 2x1152B h_lds
    const int bid = blockIdx.x;
    const int tid = threadIdx.x, lane = tid & 63;
    const int col = lane & 15, kgrp = lane >> 4;

    if (bid < GB0) {
        // ---------------- recurrent role (R4-identical, BB=4) ----------------
        const int layer = bid >> 6;
        if (layer == 0) { if (L < 1 || L > NCH) return; }
        else            { if (L < 3 || L > NCH + 2) return; }
        i8 (*h_lds)[BB * HSTR] = (i8 (*)[BB * HSTR])smem;
        const int btile = bid & 63;
        const u16* pre   = layer ? p1r : p0r;
        const i8*  wi8   = layer ? wi81 : wi80;
        const float* dq  = layer ? dq1s : dq0s;
        i8*    h_state   = layer ? hs1 : hs0;
        float* c_state   = layer ? cs1 : cs0;
        const int w = tid >> 6;
        const int b0 = btile * BB;
        const int u = w * 16 + col;          // h-unit this lane owns

        float sc[4];
        i32x4 wv[4][4];                      // 64 VGPRs resident weights
#pragma unroll
        for (int j = 0; j < 4; j++) {
            const int gt = 16 * j + w;
            sc[j] = dq[gt * 16 + col];
#pragma unroll
            for (int kc = 0; kc < 4; kc++)
                wv[j][kc] = ((const i32x4*)wi8)[(gt * 4 + kc) * 64 + lane];
        }
        if (tid < 64 * BB) {
            const int rrow = tid >> 6, cc = (tid & 63) * 4;
            *(int*)&h_lds[0][rrow * HSTR + cc] = *(const int*)&h_state[(b0 + rrow) * HID + cc];
        }
        float c_reg = c_state[(size_t)(b0 + kgrp) * HID + u];

        // pre base for this lane: btile*4096 + u*4 + kgrp   (contiguous per wave)
        const u16* pb = pre + ((size_t)btile << 12) + (u << 2) + kgrp;
        u16 pvA[4], pvB[4];
#pragma unroll
        for (int j = 0; j < 4; j++) pvA[j] = pb[j << 10];
        // h0c store base in frag layout [t][kk=u>>5][bt=btile>>2][kgrpg=(u>>3)&3][colg][e=u&7]
        const size_t h0base = ((((size_t)(w >> 1) * 16 + (btile >> 2)) * 4
                               + ((w & 1) * 2 + (col >> 3))) * 16
                              + ((btile & 3) * 4 + kgrp)) * 8 + (col & 7);
        __syncthreads();

#define REC_STEP(T, CUR, PVC, PVN) do {                                             \
        _Pragma("unroll")                                                           \
        for (int j = 0; j < 4; j++)                                                 \
            asm volatile("" : "+v"(wv[j][0]), "+v"(wv[j][1]),                       \
                              "+v"(wv[j][2]), "+v"(wv[j][3]));                      \
        i32x4 acc[4];                                                               \
        _Pragma("unroll")                                                           \
        for (int j = 0; j < 4; j++) acc[j] = (i32x4){0, 0, 0, 0};                   \
        _Pragma("unroll")                                                           \
        for (int kc = 0; kc < 4; kc++) {                                            \
            i32x4 a_ = *(const i32x4*)&h_lds[CUR][(col >> 2) * HSTR + kc * 64 + kgrp * 16]; \
            _Pragma("unroll")                                                       \
            for (int j = 0; j < 4; j++) acc[j] = MFMA_I8(a_, wv[j][kc], acc[j]);    \
        }                                                                           \
        const int tn_ = ((T) + 1 < CH) ? (T) + 1 : (T);                             \
        _Pragma("unroll")                                                           \
        for (int j = 0; j < 4; j++) PVN[j] = pb[(size_t)tn_ * PRE_TSTR + (j << 10)];\
        const float yi = fmaf((float)acc[0][0], sc[0], bf2f(PVC[0]));               \
        const float yf = fmaf((float)acc[1][0], sc[1], bf2f(PVC[1]));               \
        const float yg = fmaf((float)acc[2][0], sc[2], bf2f(PVC[2]));               \
        const float yo = fmaf((float)acc[3][0], sc[3], bf2f(PVC[3]));               \
        const float iv = sigm2(yi), fv = sigm2(yf), ov = sigm2(yo);                 \
        const float gv = tanh2(yg + yg);                                            \
        const float cn = fmaf(fv, c_reg, iv * gv);                                  \
        c_reg = cn;                                                                 \
        const float hv = ov * tanh2(cn * (2.f * LOG2E));                            \
        h_lds[(CUR) ^ 1][kgrp * HSTR + u] = (i8)__float2int_rn(hv * 127.f);         \
        if (layer == 0)                                                             \
            h0w[h0base + (size_t)(T) * H0C_TSTR] = f2bf(hv);                        \
        asm volatile("s_waitcnt lgkmcnt(0)" ::: "memory");                          \
        __builtin_amdgcn_s_barrier();                                               \
        __builtin_amdgcn_sched_barrier(0);                                          \
    } while (0)

#pragma unroll 1
        for (int t2 = 0; t2 < CH; t2 += 2) {
            REC_STEP(t2,     0, pvA, pvB);
            REC_STEP(t2 + 1, 1, pvB, pvA);
        }
#undef REC_STEP

        c_state[(size_t)(b0 + kgrp) * HID + u] = c_reg;
        if (tid < 64 * BB) {
            const int rrow = tid >> 6, cc = (tid & 63) * 4;
            *(int*)&h_state[(b0 + rrow) * HID + cc] = *(const int*)&h_lds[0][rrow * HSTR + cc];
        }
        return;
    } else if (bid < GB1) {
        // ---------------- gemm0: pre0(chunk L), operand-swapped (unchanged) ----------------
        if (L >= NCH) return;
        const int g = bid - GB0;             // 0..31
        const int tp = g >> 1, bh = g & 1;   // t' 0..15, batch half
        const int w = tid >> 6;              // wave 0..15
        const int j = w >> 2;                // pre j-chunk, constant per wave
        float bias[4];
        bf16x8 wv4[4];
#pragma unroll
        for (int tm = 0; tm < 4; tm++) {
            const int tile = w * 4 + tm;     // 16-gate tile 0..63
            bias[tm] = b0s[tile * 16 + col];
            wv4[tm] = *(const bf16x8*)&wih0f[((size_t)tile * 64 + lane) * 8];
        }
        const u16* Ab = xpad8 + ((size_t)L * CH + tp) * BATCH * 8;
#pragma unroll 1
        for (int bt = 0; bt < 8; bt++) {
            const int btg = bh * 8 + bt;     // global 16-batch tile
            bf16x8 af = {0, 0, 0, 0, 0, 0, 0, 0};   // K beyond 8 is zero-padded
            if (kgrp == 0) af = *(const bf16x8*)&Ab[(btg * 16 + col) * 8];
            f32x4 acc[4];
#pragma unroll
            for (int tm = 0; tm < 4; tm++) acc[tm] = (f32x4){bias[tm], bias[tm], bias[tm], bias[tm]};
#pragma unroll
            for (int tm = 0; tm < 4; tm++) acc[tm] = MFMA_BF16(af, wv4[tm], acc[tm]);
            // batch = btg*16+kgrp*4+rr -> (btile = btg*4+kgrp, kb = rr): one 8B store.
#pragma unroll
            for (int tm = 0; tm < 4; tm++) {
                const int ul = ((w & 3) * 4 + tm) * 16 + col;   // u within j-chunk
                const size_t off = ((((size_t)tp * 64 + btg * 4 + kgrp) * 4 + j) << 10) + (ul << 2);
                u32x2 pk;
                pk.x = (unsigned)f2bf(acc[tm][0]) | ((unsigned)f2bf(acc[tm][1]) << 16);
                pk.y = (unsigned)f2bf(acc[tm][2]) | ((unsigned)f2bf(acc[tm][3]) << 16);
                *(u32x2*)&p0w[off] = pk;
            }
        }
        return;
    } else {
        // ---------------- gemm1: pre1(chunk L-2), LDS-staged A double-buffer ----------------
        if (L < 2 || L > NCH + 1) return;
        const int g = bid - GB1;             // 0..63
        const int tp = g >> 2, j = g & 3;    // t' 0..15, j-chunk 0..3
        const int w = tid >> 6;              // wave = 16-gate tile within j
        const int gt = j * 16 + w;           // global 16-gate tile
        const float bias = b1s[gt * 16 + col];
        bf16x8 wv8[8];                       // 32 VGPRs resident weights
#pragma unroll
        for (int kk = 0; kk < 8; kk++)
            wv8[kk] = *(const bf16x8*)&wih1f[((size_t)(gt * 8 + kk) * 64 + lane) * 8];
        // A source for this t': h0r[tp][kk][bt][512]; per bt the 8KB tile is
        // shared by all 16 waves -> stage via LDS (2x L1 BW, 1/16 the traffic).
        u16* As = (u16*)smem;                // [2][8][512] u16
        const u16* Asrc = h0r + (size_t)tp * H0C_TSTR;
        const int kks = tid >> 7;            // staging slice: kk
        const int e4 = (tid & 127) * 4;      // 4 elements (8B) per thread
        {   // prologue: stage bt=0
            u32x2 st = *(const u32x2*)&Asrc[((size_t)kks * 16 + 0) * 512 + e4];
            *(u32x2*)&As[kks * 512 + e4] = st;
        }
        __syncthreads();
#pragma unroll 1
        for (int bt = 0; bt < 16; bt++) {
            const int cur = bt & 1, nxt = cur ^ 1;
            u32x2 nx;
            if (bt + 1 < 16)   // issue next tile's global load early (hidden under MFMA)
                nx = *(const u32x2*)&Asrc[((size_t)kks * 16 + bt + 1) * 512 + e4];
            bf16x8 a8[8];
#pragma unroll
            for (int kk = 0; kk < 8; kk++)
                a8[kk] = *(const bf16x8*)&As[cur * 4096 + kk * 512 + lane * 8];
            f32x4 acc = (f32x4){bias, bias, bias, bias};
#pragma unroll
            for (int kk = 0; kk < 8; kk++)
                acc = MFMA_BF16(a8[kk], wv8[kk], acc);
            const int ul = w * 16 + col;     // u within j-chunk
            const size_t off = ((((size_t)tp * 64 + bt * 4 + kgrp) * 4 + j) << 10) + (ul << 2);
            u32x2 pk;
            pk.x = (unsigned)f2bf(acc[0]) | ((unsigned)f2bf(acc[1]) << 16);
            pk.y = (unsigned)f2bf(acc[2]) | ((unsigned)f2bf(acc[3]) << 16);
            *(u32x2*)&p1w[off] = pk;
            if (bt + 1 < 16)
                *(u32x2*)&As[nxt * 4096 + kks * 512 + e4] = nx;
            __syncthreads();                 // nxt fully written; cur reads done
        }
        return;
    }
}

// ---------------------------------------------------------------------------
// head: y = sigmoid(relu(h_last) @ Wh^T + bh)
// ---------------------------------------------------------------------------
__global__ void head_kernel(const i8* __restrict__ hs1,
                            const float* __restrict__ Wh, const float* __restrict__ bh,
                            float* __restrict__ y) {
    int b = blockIdx.x;
    int l = threadIdx.x;
    const float inv127 = 1.f / 127.f;
    float hr[4];
#pragma unroll
    for (int i = 0; i < 4; ++i) hr[i] = fmaxf((float)hs1[b * HID + l + 64 * i] * inv127, 0.f);
    for (int o = 0; o < 3; ++o) {
        float s = 0.f;
#pragma unroll
        for (int i = 0; i < 4; ++i) s += hr[i] * Wh[o * HID + l + 64 * i];
        for (int off = 32; off > 0; off >>= 1) s += __shfl_down(s, off, 64);
        if (l == 0) y[b * 3 + o] = 1.f / (1.f + exp2_(-(s + bh[o]) * LOG2E));
    }
}

extern "C" void kernel_launch(void* const* d_in, const int* in_sizes, int n_in,
                              void* d_out, int out_size, void* d_ws, size_t ws_size,
                              hipStream_t stream) {
    const float* x    = (const float*)d_in[0];
    const float* Wih0 = (const float*)d_in[1];
    const float* Whh0 = (const float*)d_in[2];
    const float* bih0 = (const float*)d_in[3];
    const float* bhh0 = (const float*)d_in[4];
    const float* Wih1 = (const float*)d_in[5];
    const float* Whh1 = (const float*)d_in[6];
    const float* bih1 = (const float*)d_in[7];
    const float* bhh1 = (const float*)d_in[8];
    const float* Wh   = (const float*)d_in[9];
    const float* bh   = (const float*)d_in[10];

    char* ws = (char*)d_ws;
    i8*    wi80  = (i8*)(ws);                            // 256 KB
    i8*    wi81  = (i8*)(ws + ((size_t)256 << 10));      // 256 KB
    u16*   wih1f = (u16*)(ws + ((size_t)512 << 10));     // 512 KB
    u16*   wih0f = (u16*)(ws + ((size_t)1024 << 10));    // 64 KB
    float* qs0   = (float*)(ws + ((size_t)1088 << 10));
    float* dq0s  = (float*)(ws + ((size_t)1092 << 10));
    float* qs1   = (float*)(ws + ((size_t)1096 << 10));
    float* dq1s  = (float*)(ws + ((size_t)1100 << 10));
    float* b0s   = (float*)(ws + ((size_t)1104 << 10));
    float* b1s   = (float*)(ws + ((size_t)1108 << 10));
    i8*    hs0   = (i8*)(ws + ((size_t)1112 << 10));     // 64 KB
    i8*    hs1   = (i8*)(ws + ((size_t)1176 << 10));     // 64 KB
    float* cs0   = (float*)(ws + ((size_t)1240 << 10));  // 256 KB
    float* cs1   = (float*)(ws + ((size_t)1496 << 10));  // 256 KB
    u16*   xpad  = (u16*)(ws + ((size_t)1752 << 10));    // 2 MB  [tok][8] bf16
    u16*   h0c   = (u16*)(ws + ((size_t)3800 << 10));    // 2 x 2 MB (chunk parity)
    u16*   pre0  = (u16*)(ws + ((size_t)7896 << 10));    // 2 x 8 MB (chunk parity)
    u16*   pre1  = (u16*)(ws + ((size_t)24280 << 10));   // 2 x 8 MB -> total ~39.7 MB
    const size_t PRE_ELE = (size_t)CH * BATCH * NG;      // 4 Mi elements (8 MB)
    const size_t H0C_ELE = (size_t)CH * BATCH * HID;     // 1 Mi elements (2 MB)

    prep_a<<<4, 256, 0, stream>>>(Whh0, Whh1, bih0, bhh0, bih1, bhh1,
                                  qs0, dq0s, qs1, dq1s, b0s, b1s);
    prep_b<<<1024, 256, 0, stream>>>(x, Wih0, Whh0, Wih1, Whh1, qs0, qs1,
                                     wi80, wi81, wih1f, wih0f, hs0, hs1, cs0, cs1, xpad);
    // pipeline: gemm0(c=L) | rec0(c=L-1) | gemm1(c=L-2) | rec1(c=L-3)
    for (int L = 0; L <= NCH + 2; L++) {
        const size_t pA = (size_t)(L & 1), pB = pA ^ 1;
        stage_fused<<<NBLK, 1024, 0, stream>>>(L, xpad, wih0f, b0s, wih1f, b1s,
            pre0 + pA * PRE_ELE,        // gemm0 writes chunk L      (parity L)
            pre0 + pB * PRE_ELE,        // rec0 reads chunk L-1      (parity L-1)
            h0c  + pB * H0C_ELE,        // rec0 writes chunk L-1
            h0c  + pA * H0C_ELE,        // gemm1 reads chunk L-2     (parity L)
            pre1 + pA * PRE_ELE,        // gemm1 writes chunk L-2
            pre1 + pB * PRE_ELE,        // rec1 reads chunk L-3      (parity L-1)
            wi80, wi81, dq0s, dq1s, hs0, hs1, cs0, cs1);
    }
    head_kernel<<<BATCH, 64, 0, stream>>>(hs1, Wh, bh, (float*)d_out);
}

// Round 8
// 566.041 us; speedup vs baseline: 1.3903x; 1.1196x over previous
//
#include <hip/hip_runtime.h>
#include <hip/hip_bf16.h>

typedef unsigned short u16;
typedef signed char i8;
typedef __attribute__((ext_vector_type(4))) float f32x4;
typedef __attribute__((ext_vector_type(4))) int i32x4;
typedef __attribute__((ext_vector_type(8))) short bf16x8;
typedef __attribute__((ext_vector_type(2))) unsigned int u32x2;

#define HID 256
#define NG 1024
#define TSTEPS 512
#define BATCH 256
#define CH 32          // steps per chunk (R7 post-mortem: amortize launch+prologue)
#define NCH 16         // chunks (CH*NCH = 512)
#define BB 4           // batch rows per rec block (1 cell/lane via A-row duplication)
#define HSTR 288       // h_lds row stride bytes
#define LOG2E 1.4426950408889634f
#define PRE_TSTR 262144   // per-t' element stride in pre: 64 btiles * 4 j * 1024 (u*4+kb)
#define H0C_TSTR 65536    // per-t element stride in h0c frag layout [kk][bt][kgrp][col][e]

// fused-stage block roles
#define GB0 128        // gemm0 blocks [128,160)
#define GB1 160        // gemm1 blocks [160,224)
#define NBLK 224

#define MFMA_BF16(a, b, c) __builtin_amdgcn_mfma_f32_16x16x32_bf16((a), (b), (c), 0, 0, 0)
#define MFMA_I8(a, b, c)   __builtin_amdgcn_mfma_i32_16x16x64_i8((a), (b), (c), 0, 0, 0)

__device__ __forceinline__ float rcpf_(float x) {
#if __has_builtin(__builtin_amdgcn_rcpf)
    return __builtin_amdgcn_rcpf(x);
#else
    return 1.f / x;
#endif
}
__device__ __forceinline__ float exp2_(float x) {
#if __has_builtin(__builtin_amdgcn_exp2f)
    return __builtin_amdgcn_exp2f(x);
#else
    return exp2f(x);
#endif
}
__device__ __forceinline__ float sigm2(float y) { return rcpf_(1.f + exp2_(-y)); }
__device__ __forceinline__ float tanh2(float y2) { return fmaf(-2.f, rcpf_(exp2_(y2) + 1.f), 1.f); }
__device__ __forceinline__ u16 f2bf(float v){ __hip_bfloat16 h=__float2bfloat16(v); return __builtin_bit_cast(u16,h); }
__device__ __forceinline__ float bf2f(u16 u){ unsigned x=((unsigned)u)<<16; return __builtin_bit_cast(float,x); }

// ---------------------------------------------------------------------------
// prep_a: per-gate-row i8 scales for Whh0/Whh1; log2e folded into dequant
// scales and biases. (unchanged)
// ---------------------------------------------------------------------------
__global__ void prep_a(const float* __restrict__ Whh0, const float* __restrict__ Whh1,
                       const float* __restrict__ bih0, const float* __restrict__ bhh0,
                       const float* __restrict__ bih1, const float* __restrict__ bhh1,
                       float* __restrict__ qs0, float* __restrict__ dq0s,
                       float* __restrict__ qs1, float* __restrict__ dq1s,
                       float* __restrict__ b0s, float* __restrict__ b1s) {
    int r = blockIdx.x * blockDim.x + threadIdx.x;
    if (r >= NG) return;
    float m0 = 1e-20f, m1 = 1e-20f;
    for (int k = 0; k < HID; k++) {
        m0 = fmaxf(m0, fabsf(Whh0[r * HID + k]));
        m1 = fmaxf(m1, fabsf(Whh1[r * HID + k]));
    }
    qs0[r] = 127.f / m0;   dq0s[r] = m0 / 16129.f * LOG2E;
    qs1[r] = 127.f / m1;   dq1s[r] = m1 / 16129.f * LOG2E;
    b0s[r] = (bih0[r] + bhh0[r]) * LOG2E;
    b1s[r] = (bih1[r] + bhh1[r]) * LOG2E;
}

// ---------------------------------------------------------------------------
// prep_b: i8 frag packs for Whh0/Whh1; bf16 Wih1 frags (x LOG2E); bf16 Wih0
// frags (x LOG2E, K pad 5->32); x padded to 8 bf16/token; zeroed states.
// (unchanged)
// ---------------------------------------------------------------------------
__global__ void prep_b(const float* __restrict__ x,
    const float* __restrict__ Wih0, const float* __restrict__ Whh0,
    const float* __restrict__ Wih1, const float* __restrict__ Whh1,
    const float* __restrict__ qs0, const float* __restrict__ qs1,
    i8* __restrict__ wi80, i8* __restrict__ wi81,
    u16* __restrict__ wih1f, u16* __restrict__ wih0f,
    i8* __restrict__ hs0, i8* __restrict__ hs1,
    float* __restrict__ cs0, float* __restrict__ cs1, u16* __restrict__ xpad)
{
    const int stride = gridDim.x * blockDim.x;
    const int tid = blockIdx.x * blockDim.x + threadIdx.x;
    for (int i = tid; i < NG * HID; i += stride) {   // i8 packs (recurrent)
        int e = i & 15, l = (i >> 4) & 63, kc = (i >> 10) & 3, gt = i >> 12;
        int row = 16 * gt + (l & 15);
        int k = kc * 64 + (l >> 4) * 16 + e;
        float q0 = __builtin_rintf(Whh0[row * HID + k] * qs0[row]);
        float q1 = __builtin_rintf(Whh1[row * HID + k] * qs1[row]);
        wi80[i] = (i8)fminf(fmaxf(q0, -127.f), 127.f);
        wi81[i] = (i8)fminf(fmaxf(q1, -127.f), 127.f);
    }
    for (int i = tid; i < NG * HID; i += stride) {   // Wih1 bf16 frags, scaled
        int gt = i >> 12, kk = (i >> 9) & 7, l = (i >> 3) & 63, e = i & 7;
        wih1f[i] = f2bf(Wih1[(16 * gt + (l & 15)) * HID + kk * 32 + (l >> 4) * 8 + e] * LOG2E);
    }
    for (int i = tid; i < 32768; i += stride) {      // Wih0 bf16 frags, scaled
        int gt = i >> 9, l = (i >> 3) & 63, e = i & 7;
        int k = (l >> 4) * 8 + e;
        wih0f[i] = (k < 5) ? f2bf(Wih0[(16 * gt + (l & 15)) * 5 + k] * LOG2E) : (u16)0;
    }
    for (int i = tid; i < TSTEPS * BATCH * 8; i += stride) {  // x padded to 8, token-major
        int tok = i >> 3, k = i & 7, t = tok >> 8, b = tok & 255;
        xpad[i] = (k < 5) ? f2bf(x[((size_t)b * TSTEPS + t) * 5 + k]) : (u16)0;
    }
    for (int i = tid; i < BATCH * HID; i += stride) { hs0[i] = 0; hs1[i] = 0; cs0[i] = 0.f; cs1[i] = 0.f; }
}

// ---------------------------------------------------------------------------
// stage_fused(L): four pipeline roles on disjoint blocks (gemms overlap recs):
//   blocks [0,64):    rec layer0, chunk L-1   (reads pre0, writes h0c)
//   blocks [64,128):  rec layer1, chunk L-3   (reads pre1)
//   blocks [128,160): gemm0: pre0(chunk L)   = log2e*(Wih0 x + b0)
//   blocks [160,224): gemm1: pre1(chunk L-2) = log2e*(Wih1 h0 + b1)
//
// R7 POST-MORTEM: per-stage fixed overhead (launch gap ~2us + weight-reload
// prologue ~2us: each rec block refetches 256KB of i8 weights from L2 every
// launch) was 34 x 4 = 136us at CH=16. T(CH) model optimum is CH=32: 19
// launches, prologue amortized over 2x steps, fill/drain stages still cheap.
// Pure re-chunking -- per-step math, order, layouts identical: bit-identical.
// ---------------------------------------------------------------------------
__global__ __launch_bounds__(1024) __attribute__((amdgpu_waves_per_eu(4, 4)))
void stage_fused(int L,
    const u16* __restrict__ xpad8, const u16* __restrict__ wih0f, const float* __restrict__ b0s,
    const u16* __restrict__ wih1f, const float* __restrict__ b1s,
    u16* __restrict__ p0w, const u16* __restrict__ p0r,
    u16* __restrict__ h0w, const u16* __restrict__ h0r,
    u16* __restrict__ p1w, const u16* __restrict__ p1r,
    const i8* __restrict__ wi80, const i8* __restrict__ wi81,
    const float* __restrict__ dq0s, const float* __restrict__ dq1s,
    i8* __restrict__ hs0, i8* __restrict__ hs1,
    float* __restrict__ cs0, float* __restrict__ cs1)
{
    __shared__ __align__(16) char smem[16384];   // gemm1: 2x8KB A dbuf; rec: 2x1152B h_lds
    const int bid = blockIdx.x;
    const int tid = threadIdx.x, lane = tid & 63;
    const int col = lane & 15, kgrp = lane >> 4;

    if (bid < GB0) {
        // ---------------- recurrent role (BB=4, R7-identical math) ----------------
        const int layer = bid >> 6;
        if (layer == 0) { if (L < 1 || L > NCH) return; }
        else            { if (L < 3 || L > NCH + 2) return; }
        i8 (*h_lds)[BB * HSTR] = (i8 (*)[BB * HSTR])smem;
        const int btile = bid & 63;
        const u16* pre   = layer ? p1r : p0r;
        const i8*  wi8   = layer ? wi81 : wi80;
        const float* dq  = layer ? dq1s : dq0s;
        i8*    h_state   = layer ? hs1 : hs0;
        float* c_state   = layer ? cs1 : cs0;
        const int w = tid >> 6;
        const int b0 = btile * BB;
        const int u = w * 16 + col;          // h-unit this lane owns

        float sc[4];
        i32x4 wv[4][4];                      // 64 VGPRs resident weights
#pragma unroll
        for (int j = 0; j < 4; j++) {
            const int gt = 16 * j + w;
            sc[j] = dq[gt * 16 + col];
#pragma unroll
            for (int kc = 0; kc < 4; kc++)
                wv[j][kc] = ((const i32x4*)wi8)[(gt * 4 + kc) * 64 + lane];
        }
        if (tid < 64 * BB) {
            const int rrow = tid >> 6, cc = (tid & 63) * 4;
            *(int*)&h_lds[0][rrow * HSTR + cc] = *(const int*)&h_state[(b0 + rrow) * HID + cc];
        }
        float c_reg = c_state[(size_t)(b0 + kgrp) * HID + u];

        // pre base for this lane: btile*4096 + u*4 + kgrp   (contiguous per wave)
        const u16* pb = pre + ((size_t)btile << 12) + (u << 2) + kgrp;
        u16 pvA[4], pvB[4];
#pragma unroll
        for (int j = 0; j < 4; j++) pvA[j] = pb[j << 10];
        // h0c store base in frag layout [t][kk=u>>5][bt=btile>>2][kgrpg=(u>>3)&3][colg][e=u&7]
        const size_t h0base = ((((size_t)(w >> 1) * 16 + (btile >> 2)) * 4
                               + ((w & 1) * 2 + (col >> 3))) * 16
                              + ((btile & 3) * 4 + kgrp)) * 8 + (col & 7);
        __syncthreads();

#define REC_STEP(T, CUR, PVC, PVN) do {                                             \
        _Pragma("unroll")                                                           \
        for (int j = 0; j < 4; j++)                                                 \
            asm volatile("" : "+v"(wv[j][0]), "+v"(wv[j][1]),                       \
                              "+v"(wv[j][2]), "+v"(wv[j][3]));                      \
        i32x4 acc[4];                                                               \
        _Pragma("unroll")                                                           \
        for (int j = 0; j < 4; j++) acc[j] = (i32x4){0, 0, 0, 0};                   \
        _Pragma("unroll")                                                           \
        for (int kc = 0; kc < 4; kc++) {                                            \
            i32x4 a_ = *(const i32x4*)&h_lds[CUR][(col >> 2) * HSTR + kc * 64 + kgrp * 16]; \
            _Pragma("unroll")                                                       \
            for (int j = 0; j < 4; j++) acc[j] = MFMA_I8(a_, wv[j][kc], acc[j]);    \
        }                                                                           \
        const int tn_ = ((T) + 1 < CH) ? (T) + 1 : (T);                             \
        _Pragma("unroll")                                                           \
        for (int j = 0; j < 4; j++) PVN[j] = pb[(size_t)tn_ * PRE_TSTR + (j << 10)];\
        const float yi = fmaf((float)acc[0][0], sc[0], bf2f(PVC[0]));               \
        const float yf = fmaf((float)acc[1][0], sc[1], bf2f(PVC[1]));               \
        const float yg = fmaf((float)acc[2][0], sc[2], bf2f(PVC[2]));               \
        const float yo = fmaf((float)acc[3][0], sc[3], bf2f(PVC[3]));               \
        const float iv = sigm2(yi), fv = sigm2(yf), ov = sigm2(yo);                 \
        const float gv = tanh2(yg + yg);                                            \
        const float cn = fmaf(fv, c_reg, iv * gv);                                  \
        c_reg = cn;                                                                 \
        const float hv = ov * tanh2(cn * (2.f * LOG2E));                            \
        h_lds[(CUR) ^ 1][kgrp * HSTR + u] = (i8)__float2int_rn(hv * 127.f);         \
        if (layer == 0)                                                             \
            h0w[h0base + (size_t)(T) * H0C_TSTR] = f2bf(hv);                        \
        asm volatile("s_waitcnt lgkmcnt(0)" ::: "memory");                          \
        __builtin_amdgcn_s_barrier();                                               \
        __builtin_amdgcn_sched_barrier(0);                                          \
    } while (0)

#pragma unroll 1
        for (int t2 = 0; t2 < CH; t2 += 2) {
            REC_STEP(t2,     0, pvA, pvB);
            REC_STEP(t2 + 1, 1, pvB, pvA);
        }
#undef REC_STEP

        c_state[(size_t)(b0 + kgrp) * HID + u] = c_reg;
        if (tid < 64 * BB) {
            const int rrow = tid >> 6, cc = (tid & 63) * 4;
            *(int*)&h_state[(b0 + rrow) * HID + cc] = *(const int*)&h_lds[0][rrow * HSTR + cc];
        }
        return;
    } else if (bid < GB1) {
        // ---------------- gemm0: pre0(chunk L), 32 blocks x 1 tp x 16 bt ----------------
        if (L >= NCH) return;
        const int tp = bid - GB0;            // t' 0..31
        const int w = tid >> 6;              // wave 0..15
        const int j = w >> 2;                // pre j-chunk, constant per wave
        float bias[4];
        bf16x8 wv4[4];
#pragma unroll
        for (int tm = 0; tm < 4; tm++) {
            const int tile = w * 4 + tm;     // 16-gate tile 0..63
            bias[tm] = b0s[tile * 16 + col];
            wv4[tm] = *(const bf16x8*)&wih0f[((size_t)tile * 64 + lane) * 8];
        }
        const u16* Ab = xpad8 + ((size_t)L * CH + tp) * BATCH * 8;
#pragma unroll 1
        for (int btg = 0; btg < 16; btg++) {
            bf16x8 af = {0, 0, 0, 0, 0, 0, 0, 0};   // K beyond 8 is zero-padded
            if (kgrp == 0) af = *(const bf16x8*)&Ab[(btg * 16 + col) * 8];
            f32x4 acc[4];
#pragma unroll
            for (int tm = 0; tm < 4; tm++) acc[tm] = (f32x4){bias[tm], bias[tm], bias[tm], bias[tm]};
#pragma unroll
            for (int tm = 0; tm < 4; tm++) acc[tm] = MFMA_BF16(af, wv4[tm], acc[tm]);
            // batch = btg*16+kgrp*4+rr -> (btile = btg*4+kgrp, kb = rr): one 8B store.
#pragma unroll
            for (int tm = 0; tm < 4; tm++) {
                const int ul = ((w & 3) * 4 + tm) * 16 + col;   // u within j-chunk
                const size_t off = ((((size_t)tp * 64 + btg * 4 + kgrp) * 4 + j) << 10) + (ul << 2);
                u32x2 pk;
                pk.x = (unsigned)f2bf(acc[tm][0]) | ((unsigned)f2bf(acc[tm][1]) << 16);
                pk.y = (unsigned)f2bf(acc[tm][2]) | ((unsigned)f2bf(acc[tm][3]) << 16);
                *(u32x2*)&p0w[off] = pk;
            }
        }
        return;
    } else {
        // ---------------- gemm1: pre1(chunk L-2), 64 blocks x 2 tp, LDS-staged A ----------------
        if (L < 2 || L > NCH + 1) return;
        const int g = bid - GB1;             // 0..63
        const int j = g & 3;                 // j-chunk 0..3
        const int tpb = (g >> 2) * 2;        // t' base: 0,2,..,30
        const int w = tid >> 6;              // wave = 16-gate tile within j
        const int gt = j * 16 + w;           // global 16-gate tile
        const float bias = b1s[gt * 16 + col];
        bf16x8 wv8[8];                       // 32 VGPRs resident weights
#pragma unroll
        for (int kk = 0; kk < 8; kk++)
            wv8[kk] = *(const bf16x8*)&wih1f[((size_t)(gt * 8 + kk) * 64 + lane) * 8];
        u16* As = (u16*)smem;                // [2][8][512] u16 double buffer
        const int kks = tid >> 7;            // staging slice: kk
        const int e4 = (tid & 127) * 4;      // 4 elements (8B) per thread
#pragma unroll 1
        for (int tpi = 0; tpi < 2; tpi++) {
            const int tp = tpb + tpi;
            const u16* Asrc = h0r + (size_t)tp * H0C_TSTR;
            {   // prologue: stage bt=0 into buf0
                u32x2 st = *(const u32x2*)&Asrc[((size_t)kks * 16 + 0) * 512 + e4];
                *(u32x2*)&As[kks * 512 + e4] = st;
            }
            __syncthreads();
#pragma unroll 1
            for (int bt = 0; bt < 16; bt++) {
                const int cur = bt & 1, nxt = cur ^ 1;
                u32x2 nx;
                if (bt + 1 < 16)   // issue next tile's global load early (hidden under MFMA)
                    nx = *(const u32x2*)&Asrc[((size_t)kks * 16 + bt + 1) * 512 + e4];
                bf16x8 a8[8];
#pragma unroll
                for (int kk = 0; kk < 8; kk++)
                    a8[kk] = *(const bf16x8*)&As[cur * 4096 + kk * 512 + lane * 8];
                f32x4 acc = (f32x4){bias, bias, bias, bias};
#pragma unroll
                for (int kk = 0; kk < 8; kk++)
                    acc = MFMA_BF16(a8[kk], wv8[kk], acc);
                const int ul = w * 16 + col;     // u within j-chunk
                const size_t off = ((((size_t)tp * 64 + bt * 4 + kgrp) * 4 + j) << 10) + (ul << 2);
                u32x2 pk;
                pk.x = (unsigned)f2bf(acc[0]) | ((unsigned)f2bf(acc[1]) << 16);
                pk.y = (unsigned)f2bf(acc[2]) | ((unsigned)f2bf(acc[3]) << 16);
                *(u32x2*)&p1w[off] = pk;
                if (bt + 1 < 16)
                    *(u32x2*)&As[nxt * 4096 + kks * 512 + e4] = nx;
                __syncthreads();                 // nxt fully written; cur reads done
            }
        }
        return;
    }
}

// ---------------------------------------------------------------------------
// head: y = sigmoid(relu(h_last) @ Wh^T + bh)
// ---------------------------------------------------------------------------
__global__ void head_kernel(const i8* __restrict__ hs1,
                            const float* __restrict__ Wh, const float* __restrict__ bh,
                            float* __restrict__ y) {
    int b = blockIdx.x;
    int l = threadIdx.x;
    const float inv127 = 1.f / 127.f;
    float hr[4];
#pragma unroll
    for (int i = 0; i < 4; ++i) hr[i] = fmaxf((float)hs1[b * HID + l + 64 * i] * inv127, 0.f);
    for (int o = 0; o < 3; ++o) {
        float s = 0.f;
#pragma unroll
        for (int i = 0; i < 4; ++i) s += hr[i] * Wh[o * HID + l + 64 * i];
        for (int off = 32; off > 0; off >>= 1) s += __shfl_down(s, off, 64);
        if (l == 0) y[b * 3 + o] = 1.f / (1.f + exp2_(-(s + bh[o]) * LOG2E));
    }
}

extern "C" void kernel_launch(void* const* d_in, const int* in_sizes, int n_in,
                              void* d_out, int out_size, void* d_ws, size_t ws_size,
                              hipStream_t stream) {
    const float* x    = (const float*)d_in[0];
    const float* Wih0 = (const float*)d_in[1];
    const float* Whh0 = (const float*)d_in[2];
    const float* bih0 = (const float*)d_in[3];
    const float* bhh0 = (const float*)d_in[4];
    const float* Wih1 = (const float*)d_in[5];
    const float* Whh1 = (const float*)d_in[6];
    const float* bih1 = (const float*)d_in[7];
    const float* bhh1 = (const float*)d_in[8];
    const float* Wh   = (const float*)d_in[9];
    const float* bh   = (const float*)d_in[10];

    char* ws = (char*)d_ws;
    i8*    wi80  = (i8*)(ws);                            // 256 KB
    i8*    wi81  = (i8*)(ws + ((size_t)256 << 10));      // 256 KB
    u16*   wih1f = (u16*)(ws + ((size_t)512 << 10));     // 512 KB
    u16*   wih0f = (u16*)(ws + ((size_t)1024 << 10));    // 64 KB
    float* qs0   = (float*)(ws + ((size_t)1088 << 10));
    float* dq0s  = (float*)(ws + ((size_t)1092 << 10));
    float* qs1   = (float*)(ws + ((size_t)1096 << 10));
    float* dq1s  = (float*)(ws + ((size_t)1100 << 10));
    float* b0s   = (float*)(ws + ((size_t)1104 << 10));
    float* b1s   = (float*)(ws + ((size_t)1108 << 10));
    i8*    hs0   = (i8*)(ws + ((size_t)1112 << 10));     // 64 KB
    i8*    hs1   = (i8*)(ws + ((size_t)1176 << 10));     // 64 KB
    float* cs0   = (float*)(ws + ((size_t)1240 << 10));  // 256 KB
    float* cs1   = (float*)(ws + ((size_t)1496 << 10));  // 256 KB
    u16*   xpad  = (u16*)(ws + ((size_t)1752 << 10));    // 2 MB  [tok][8] bf16
    u16*   h0c   = (u16*)(ws + ((size_t)4096 << 10));    // 2 x 4 MB (chunk parity)
    u16*   pre0  = (u16*)(ws + ((size_t)12288 << 10));   // 2 x 16 MB (chunk parity)
    u16*   pre1  = (u16*)(ws + ((size_t)45056 << 10));   // 2 x 16 MB -> total ~76 MB
    const size_t PRE_ELE = (size_t)CH * BATCH * NG;      // 8 Mi elements (16 MB)
    const size_t H0C_ELE = (size_t)CH * BATCH * HID;     // 2 Mi elements (4 MB)

    prep_a<<<4, 256, 0, stream>>>(Whh0, Whh1, bih0, bhh0, bih1, bhh1,
                                  qs0, dq0s, qs1, dq1s, b0s, b1s);
    prep_b<<<1024, 256, 0, stream>>>(x, Wih0, Whh0, Wih1, Whh1, qs0, qs1,
                                     wi80, wi81, wih1f, wih0f, hs0, hs1, cs0, cs1, xpad);
    // pipeline: gemm0(c=L) | rec0(c=L-1) | gemm1(c=L-2) | rec1(c=L-3)
    for (int L = 0; L <= NCH + 2; L++) {
        const size_t pA = (size_t)(L & 1), pB = pA ^ 1;
        stage_fused<<<NBLK, 1024, 0, stream>>>(L, xpad, wih0f, b0s, wih1f, b1s,
            pre0 + pA * PRE_ELE,        // gemm0 writes chunk L      (parity L)
            pre0 + pB * PRE_ELE,        // rec0 reads chunk L-1      (parity L-1)
            h0c  + pB * H0C_ELE,        // rec0 writes chunk L-1
            h0c  + pA * H0C_ELE,        // gemm1 reads chunk L-2     (parity L)
            pre1 + pA * PRE_ELE,        // gemm1 writes chunk L-2
            pre1 + pB * PRE_ELE,        // rec1 reads chunk L-3      (parity L-1)
            wi80, wi81, dq0s, dq1s, hs0, hs1, cs0, cs1);
    }
    head_kernel<<<BATCH, 64, 0, stream>>>(hs1, Wh, bh, (float*)d_out);
}